// Round 5
// baseline (149.929 us; speedup 1.0000x reference)
//
#include <hip/hip_runtime.h>

typedef _Float16 f16x8 __attribute__((ext_vector_type(8)));
typedef __fp16   fp16x2r __attribute__((ext_vector_type(2)));   // cvt_pkrtz return type
typedef float    f32x4 __attribute__((ext_vector_type(4)));

#define MFMA(a, b, c) __builtin_amdgcn_mfma_f32_16x16x32_f16((a), (b), (c), 0, 0, 0)

__device__ inline f16x8 zero8() {
    f16x8 z;
#pragma unroll
    for (int i = 0; i < 8; ++i) z[i] = (_Float16)0.0f;
    return z;
}

// layer-1 pack: rtn casts (matches R10/R12/R13 h1 numerics exactly)
__device__ inline f16x8 relu_pack8_rtn(f32x4 lo, f32x4 hi) {
    f16x8 v;
#pragma unroll
    for (int i = 0; i < 4; ++i) {
        v[i]     = (_Float16)fmaxf(lo[i], 0.f);
        v[i + 4] = (_Float16)fmaxf(hi[i], 0.f);
    }
    return v;
}

// layer-2 pack: f32 relu then cvt_pkrtz (matches R10/R12/R13 h2 numerics)
__device__ inline f16x8 relu_pack8_rtz(f32x4 lo, f32x4 hi) {
    const fp16x2r p0 = __builtin_amdgcn_cvt_pkrtz(fmaxf(lo[0], 0.f), fmaxf(lo[1], 0.f));
    const fp16x2r p1 = __builtin_amdgcn_cvt_pkrtz(fmaxf(lo[2], 0.f), fmaxf(lo[3], 0.f));
    const fp16x2r p2 = __builtin_amdgcn_cvt_pkrtz(fmaxf(hi[0], 0.f), fmaxf(hi[1], 0.f));
    const fp16x2r p3 = __builtin_amdgcn_cvt_pkrtz(fmaxf(hi[2], 0.f), fmaxf(hi[3], 0.f));
    uint4 u = { __builtin_bit_cast(unsigned int, p0), __builtin_bit_cast(unsigned int, p1),
                __builtin_bit_cast(unsigned int, p2), __builtin_bit_cast(unsigned int, p3) };
    return __builtin_bit_cast(f16x8, u);
}

// R16: R13 (PASSED, absmax 0.0078) byte-for-byte; ONLY the launch grid changes
//   512 -> 768 to lift the residency cap from 2 to 3 blocks/CU.
//   R14/R15 post-mortem: BOTH MFMA-region restructurings miscompiled
//   (R14 '#pragma unroll 1' s3-loop -> nondeterministic absmax 0.031-0.039;
//   R15 sched_barrier(0) hand-unroll -> 0.0625). Math was identical to R13 in
//   both (biases are all zero). BAN LIST for this target/toolchain:
//     - __launch_bounds__ min-waves >= 2            (5/5 miscompiles)
//     - serialized / runtime-trip loops around MFMA  (R14)
//     - sched_barrier in MFMA regions                (R15)
//   Residency arithmetic for R13's resources (VGPR 148, LDS 40448):
//     VGPR: floor(512/148) = 3 waves/SIMD  -> 3 blocks/CU (1 wave/SIMD/block)
//     LDS : 3 x 40448 = 121344 <= 163840   -> 3 blocks/CU
//     grid: 768 = 3 x 256 CU               -> exactly 3 blocks/CU
//   Grid change is semantics-free: grid-stride partitions tiles uniquely,
//   no cross-block state exists.
//   K-slot permutation (R12-verified, both sides agree):
//     slot(s, quad, j) == channel 32*s + 16*(j>>2) + 4*quad + (j&3)
// Fragment maps: R3-hardware-verified canonical (A m=l15,k=8q+j; B k=8q+j,
// n=l15; D m=4q+r, n=l15).
__global__ __launch_bounds__(256, 1)
void DeformationCorrector_78967268704761_kernel(
        const float* __restrict__ F,
        const float* __restrict__ W1, const float* __restrict__ b1,
        const float* __restrict__ W2, const float* __restrict__ b2,
        const float* __restrict__ W3, const float* __restrict__ b3,
        float* __restrict__ out, int N)
{
    __shared__ __align__(16) _Float16 W2A[8][4][64][8]; // 32 KB  W2 A-frags (slot-permuted)
    __shared__ __align__(16) _Float16 W1A[8][16][8];    // 2 KB   W1 A-frags (k<7 -> W1, k=7 -> b1)
    __shared__ __align__(16) _Float16 W3A[4][16][8];    // 1 KB   W3 A-frags (slot-permuted, l15<4)
    __shared__ __align__(16) float    b2L[128];         // 0.5 KB b2 for C-operand init
    __shared__ __align__(16) float    b3L[4];           // 16 B   (kept for layout parity; unused math)
    __shared__ __align__(16) _Float16 invL[4][64][8];   // 4 KB   per-wave invariants; aliased as
                                                        //        epilogue x-scratch (16 B/point)

    const int tid  = threadIdx.x;
    const int lane = tid & 63;
    const int w    = tid >> 6;
    const int l15  = tid & 15;
    const int quad = (tid >> 4) & 3;

    // ---------------- weight pre-pack (once per block) ----------------
    // W2A[mt2][s][q*16+n15][j] = W2[k][n] with k = 32s + 16(j>>2) + 4q + (j&3)
    for (int m = tid; m < 128 * 128; m += 256) {
        const int k = m >> 7, n = m & 127;
        const int s = k >> 5, j = ((k >> 4) & 1) * 4 + (k & 3), q = (k >> 2) & 3;
        W2A[n >> 4][s][q * 16 + (n & 15)][j] = (_Float16)W2[m];
    }
    for (int f = tid; f < 1024; f += 256) {             // W1A[mt][l15][j] = W1[j][mt*16+l15] (j=7 -> b1)
        const int mt = f >> 7, n15 = (f >> 3) & 15, j = f & 7;
        W1A[mt][n15][j] = (_Float16)((j < 7) ? W1[j * 128 + mt * 16 + n15]
                                             : b1[mt * 16 + n15]);
    }
    for (int f = tid; f < 512; f += 256) {              // W3A[s3][q*4+c3][j] = W3[ch2][c3]
        const int s3 = f >> 7, idx = (f >> 3) & 15, j = f & 7;
        const int q = idx >> 2, c3 = idx & 3;
        const int ch2 = (2 * s3 + (j >> 2)) * 16 + q * 4 + (j & 3);
        W3A[s3][idx][j] = (_Float16)W3[ch2 * 4 + c3];
    }
    if (tid < 128) b2L[tid] = b2[tid];
    if (tid < 4)   b3L[tid] = b3[tid];
    f32x4 b3i;                                           // acc3 C-init: b3 on quad0 rows (R13-verified)
    {
        const float4 t = *(const float4*)b3;
        b3i = (quad == 0) ? (f32x4){t.x, t.y, t.z, t.w} : (f32x4){0.f, 0.f, 0.f, 0.f};
    }
    __syncthreads();   // only barrier; all main-loop LDS traffic is wave-private or read-only

    const int ntiles = (N + 255) >> 8;
    const int stride = (int)gridDim.x;

    // prime the F prefetch for the first tile
    float a, b, c, d;
    {
        const int p0 = blockIdx.x * 256 + tid;
        if (blockIdx.x < ntiles && p0 < N) {
            const float4 f4 = *(const float4*)(F + 4ll * p0);
            a = f4.x; b = f4.y; c = f4.z; d = f4.w;
        } else { a = 1.f; b = 0.f; c = 0.f; d = 1.f; }
    }

    for (int tile = blockIdx.x; tile < ntiles; tile += stride) {
        // ---------------- prefetch next tile's F (overlaps whole body) ----------------
        float na = 1.f, nb = 0.f, nc = 0.f, nd = 1.f;
        {
            const int pn = (tile + stride) * 256 + tid;
            if (tile + stride < ntiles && pn < N) {
                const float4 f4 = *(const float4*)(F + 4ll * pn);
                na = f4.x; nb = f4.y; nc = f4.z; nd = f4.w;
            }
        }
        const int p = tile * 256 + tid;

        // ---------------- invariants + polar (fp32, verified) ----------------
        const float x1 = a + d, y1 = c - b, x2 = a - d, y2 = c + b;
        const float h1v = sqrtf(x1 * x1 + y1 * y1);
        const float h2v = sqrtf(x2 * x2 + y2 * y2);
        const float s1 = 0.5f * (h1v + h2v), s2 = 0.5f * (h1v - h2v);
        const float ir = 1.0f / h1v;
        const float Rc = x1 * ir, Rs = y1 * ir;
        f16x8 iv;
        iv[0] = (_Float16)(s1 - 1.f);
        iv[1] = (_Float16)(s2 - 1.f);
        iv[2] = (_Float16)(a * a + c * c - 1.f);
        const float i3 = a * b + c * d;
        iv[3] = (_Float16)i3;
        iv[4] = (_Float16)i3;
        iv[5] = (_Float16)(b * b + d * d - 1.f);
        iv[6] = (_Float16)(a * d - b * c - 1.f);
        iv[7] = (_Float16)1.0f;
        *(f16x8*)(&invL[w][lane][0]) = iv;

        // ---------------- two 32-point half-passes (keep register state small) ----------
#pragma unroll 1
        for (int half = 0; half < 2; ++half) {
            // B1 frags: B[k=8q+j][n=l15] = inv_k(point (2*half+nt2)*16+l15); quad0 only
            f16x8 B1[2];
#pragma unroll
            for (int nt2 = 0; nt2 < 2; ++nt2)
                B1[nt2] = (quad == 0)
                    ? *(const f16x8*)(&invL[w][(2 * half + nt2) * 16 + l15][0])
                    : zero8();

            // ---- layer 1 (transposed): build this half's B2 in registers ----
            f16x8 B2[4][2];   // [s][nt2] = h1 B-frags, 32 VGPRs
#pragma unroll
            for (int s = 0; s < 4; ++s) {
                const f16x8 aLo = (quad == 0) ? *(const f16x8*)(&W1A[2 * s][l15][0])     : zero8();
                const f16x8 aHi = (quad == 0) ? *(const f16x8*)(&W1A[2 * s + 1][l15][0]) : zero8();
#pragma unroll
                for (int nt2 = 0; nt2 < 2; ++nt2) {
                    const f32x4 cz  = {0.f, 0.f, 0.f, 0.f};
                    const f32x4 dLo = MFMA(aLo, B1[nt2], cz);   // ch = 32s    + 4q + r
                    const f32x4 dHi = MFMA(aHi, B1[nt2], cz);   // ch = 32s+16 + 4q + r
                    B2[s][nt2] = relu_pack8_rtn(dLo, dHi);
                }
            }

            // ---- layers 2+3 fused, register-chained ----
            f32x4 acc3[2];
#pragma unroll
            for (int nt2 = 0; nt2 < 2; ++nt2) acc3[nt2] = b3i;

#pragma unroll
            for (int s3 = 0; s3 < 4; ++s3) {               // mt2 pair (2*s3, 2*s3+1)
                f32x4 accE[2], accO[2];
                {
                    const f32x4 bvE = *(const f32x4*)(&b2L[(2 * s3) * 16 + quad * 4]);
                    const f32x4 bvO = *(const f32x4*)(&b2L[(2 * s3 + 1) * 16 + quad * 4]);
#pragma unroll
                    for (int nt2 = 0; nt2 < 2; ++nt2) { accE[nt2] = bvE; accO[nt2] = bvO; }
                }
#pragma unroll
                for (int s = 0; s < 4; ++s) {
                    const f16x8 aE = *(const f16x8*)(&W2A[2 * s3][s][lane][0]);
                    const f16x8 aO = *(const f16x8*)(&W2A[2 * s3 + 1][s][lane][0]);
#pragma unroll
                    for (int nt2 = 0; nt2 < 2; ++nt2) {
                        accE[nt2] = MFMA(aE, B2[s][nt2], accE[nt2]);
                        accO[nt2] = MFMA(aO, B2[s][nt2], accO[nt2]);
                    }
                }
                const f16x8 a3 = (l15 < 4) ? *(const f16x8*)(&W3A[s3][quad * 4 + l15][0]) : zero8();
#pragma unroll
                for (int nt2 = 0; nt2 < 2; ++nt2) {
                    const f16x8 b3f = relu_pack8_rtz(accE[nt2], accO[nt2]);
                    acc3[nt2] = MFMA(a3, b3f, acc3[nt2]);
                }
            }

            // stage this half's x into invL rows [32*half, 32*half+32) (wave-private.
            // half-1's B1 reads touch rows 32..63, written-x rows 0..31: disjoint, in
            // program order within the wave -> no race.)
            if (quad == 0) {
#pragma unroll
                for (int nt2 = 0; nt2 < 2; ++nt2)
                    *(f16x8*)(&invL[w][(2 * half + nt2) * 16 + l15][0]) =
                        __builtin_bit_cast(f16x8, acc3[nt2]);
            }
        }

        // ---------------- epilogue: x via invL alias -> R@x + F ----------------
        const f32x4 xv = __builtin_bit_cast(f32x4, *(const f16x8*)(&invL[w][lane][0]));
        const float xm  = 0.5f * (xv[1] + xv[2]);
        const float d00 = Rc * xv[0] - Rs * xm;
        const float d01 = Rc * xm    - Rs * xv[3];
        const float d10 = Rs * xv[0] + Rc * xm;
        const float d11 = Rs * xm    + Rc * xv[3];
        if (p < N) {
            float4 o;
            o.x = a + d00; o.y = b + d01; o.z = c + d10; o.w = d + d11;
            *(float4*)(out + 4ll * p) = o;
        }

        // rotate prefetched F into place for the next tile
        a = na; b = nb; c = nc; d = nd;
    }
}

extern "C" void kernel_launch(void* const* d_in, const int* in_sizes, int n_in,
                              void* d_out, int out_size, void* d_ws, size_t ws_size,
                              hipStream_t stream) {
    const float* F  = (const float*)d_in[0];
    const float* W1 = (const float*)d_in[1];
    const float* b1 = (const float*)d_in[2];
    const float* W2 = (const float*)d_in[3];
    const float* b2 = (const float*)d_in[4];
    const float* W3 = (const float*)d_in[5];
    const float* b3 = (const float*)d_in[6];
    float* out = (float*)d_out;
    const int N = in_sizes[0] / 4;
    const int ntiles = (N + 255) / 256;
    // 3 blocks/CU x 256 CU: VGPR (floor(512/148)=3 waves/SIMD) and LDS
    // (3 x 40448 = 121344 <= 163840) both admit 3; grid-stride keeps
    // correctness at any actual residency.
    const int grid = ntiles < 768 ? ntiles : 768;
    DeformationCorrector_78967268704761_kernel<<<grid, 256, 0, stream>>>(
        F, W1, b1, W2, b2, W3, b3, out, N);
}

// Round 6
// 133.716 us; speedup vs baseline: 1.1212x; 1.1212x over previous
//
#include <hip/hip_runtime.h>

typedef _Float16 f16x8 __attribute__((ext_vector_type(8)));
typedef __fp16   fp16x2r __attribute__((ext_vector_type(2)));   // cvt_pkrtz return type
typedef float    f32x4 __attribute__((ext_vector_type(4)));

#define MFMA(a, b, c) __builtin_amdgcn_mfma_f32_16x16x32_f16((a), (b), (c), 0, 0, 0)

__device__ inline f16x8 zero8() {
    f16x8 z;
#pragma unroll
    for (int i = 0; i < 8; ++i) z[i] = (_Float16)0.0f;
    return z;
}

// layer-1 pack: rtn casts (matches R10/R12/R13 h1 numerics exactly)
__device__ inline f16x8 relu_pack8_rtn(f32x4 lo, f32x4 hi) {
    f16x8 v;
#pragma unroll
    for (int i = 0; i < 4; ++i) {
        v[i]     = (_Float16)fmaxf(lo[i], 0.f);
        v[i + 4] = (_Float16)fmaxf(hi[i], 0.f);
    }
    return v;
}

// layer-2 pack: f32 relu then cvt_pkrtz (matches R10/R12/R13 h2 numerics)
__device__ inline f16x8 relu_pack8_rtz(f32x4 lo, f32x4 hi) {
    const fp16x2r p0 = __builtin_amdgcn_cvt_pkrtz(fmaxf(lo[0], 0.f), fmaxf(lo[1], 0.f));
    const fp16x2r p1 = __builtin_amdgcn_cvt_pkrtz(fmaxf(lo[2], 0.f), fmaxf(lo[3], 0.f));
    const fp16x2r p2 = __builtin_amdgcn_cvt_pkrtz(fmaxf(hi[0], 0.f), fmaxf(hi[1], 0.f));
    const fp16x2r p3 = __builtin_amdgcn_cvt_pkrtz(fmaxf(hi[2], 0.f), fmaxf(hi[3], 0.f));
    uint4 u = { __builtin_bit_cast(unsigned int, p0), __builtin_bit_cast(unsigned int, p1),
                __builtin_bit_cast(unsigned int, p2), __builtin_bit_cast(unsigned int, p3) };
    return __builtin_bit_cast(f16x8, u);
}

// R17: QUARTER-pass register-chained MLP — R13's verified chain with half the
//   live register state, targeting the arch-VGPR <= 128 residency gate.
//   Session laws (R10..R16 evidence):
//     - VGPR <= 128  -> 2x residency of VGPR 148-200 (R10 18.3% occ vs 10.2%)
//     - grid is NOT a lever: R16 (grid 768) left occupancy at 10.3% and only
//       added per-block prepack overhead (+4.5us). Grid stays 512.
//     - BAN: __launch_bounds__ min-waves >= 2 (5/5 miscompiles)
//     - BAN: serialized loops with LOOP-CARRIED MFMA accumulators (R14,
//       nondet absmax). R13's pass-loop shape (acc born+consumed inside each
//       iteration, only LDS carried) passed twice -> reused here verbatim.
//     - BAN: sched_barrier in MFMA regions (R15, absmax 0.0625).
//   Changes vs R13 (all register trims, zero numeric change for this problem):
//     (1) 32-point halves -> 16-point quarters: B2[4][2]->B2[4] (32->16 regs),
//         accE/O[2]->scalar pair (16->8), acc3[2]->1 (8->4).
//     (2) F software prefetch dropped (~8 regs; TLP covers once residency
//         recovers).
//     (3) b3 C-init (persistent b3i, 4 regs) -> transient add from b3L at
//         x-staging (pre-symmetrize, R10-verified ordering; b3=0 here anyway).
//   Cost: W1A/W2A/W3A fragment re-reads x2 vs R13 (~+120 conflict-free b128
//   reads/wave-tile) — hidden by recovered TLP.
//   K-slot permutation (R12-verified, both sides agree):
//     slot(s, quad, j) == channel 32*s + 16*(j>>2) + 4*quad + (j&3)
// Fragment maps: R3-hardware-verified canonical (A m=l15,k=8q+j; B k=8q+j,
// n=l15; D m=4q+r, n=l15).
__global__ __launch_bounds__(256, 1)
void DeformationCorrector_78967268704761_kernel(
        const float* __restrict__ F,
        const float* __restrict__ W1, const float* __restrict__ b1,
        const float* __restrict__ W2, const float* __restrict__ b2,
        const float* __restrict__ W3, const float* __restrict__ b3,
        float* __restrict__ out, int N)
{
    __shared__ __align__(16) _Float16 W2A[8][4][64][8]; // 32 KB  W2 A-frags (slot-permuted)
    __shared__ __align__(16) _Float16 W1A[8][16][8];    // 2 KB   W1 A-frags (k<7 -> W1, k=7 -> b1)
    __shared__ __align__(16) _Float16 W3A[4][16][8];    // 1 KB   W3 A-frags (slot-permuted, l15<4)
    __shared__ __align__(16) float    b2L[128];         // 0.5 KB b2 for C-operand init
    __shared__ __align__(16) float    b3L[4];           // 16 B   b3 for x-staging add
    __shared__ __align__(16) _Float16 invL[4][64][8];   // 4 KB   per-wave invariants; aliased as
                                                        //        x-scratch (16 B/point)

    const int tid  = threadIdx.x;
    const int lane = tid & 63;
    const int w    = tid >> 6;
    const int l15  = tid & 15;
    const int quad = (tid >> 4) & 3;

    // ---------------- weight pre-pack (once per block) ----------------
    // W2A[mt2][s][q*16+n15][j] = W2[k][n] with k = 32s + 16(j>>2) + 4q + (j&3)
    for (int m = tid; m < 128 * 128; m += 256) {
        const int k = m >> 7, n = m & 127;
        const int s = k >> 5, j = ((k >> 4) & 1) * 4 + (k & 3), q = (k >> 2) & 3;
        W2A[n >> 4][s][q * 16 + (n & 15)][j] = (_Float16)W2[m];
    }
    for (int f = tid; f < 1024; f += 256) {             // W1A[mt][l15][j] = W1[j][mt*16+l15] (j=7 -> b1)
        const int mt = f >> 7, n15 = (f >> 3) & 15, j = f & 7;
        W1A[mt][n15][j] = (_Float16)((j < 7) ? W1[j * 128 + mt * 16 + n15]
                                             : b1[mt * 16 + n15]);
    }
    for (int f = tid; f < 512; f += 256) {              // W3A[s3][q*4+c3][j] = W3[ch2][c3]
        const int s3 = f >> 7, idx = (f >> 3) & 15, j = f & 7;
        const int q = idx >> 2, c3 = idx & 3;
        const int ch2 = (2 * s3 + (j >> 2)) * 16 + q * 4 + (j & 3);
        W3A[s3][idx][j] = (_Float16)W3[ch2 * 4 + c3];
    }
    if (tid < 128) b2L[tid] = b2[tid];
    if (tid < 4)   b3L[tid] = b3[tid];
    __syncthreads();   // only barrier; all main-loop LDS traffic is wave-private or read-only

    const int ntiles = (N + 255) >> 8;
    const int stride = (int)gridDim.x;

    for (int tile = blockIdx.x; tile < ntiles; tile += stride) {
        const int p = tile * 256 + tid;

        // ---------------- F load (no SW prefetch: register trim R17-(2)) ----------
        float a, b, c, d;
        if (p < N) {
            const float4 f4 = *(const float4*)(F + 4ll * p);
            a = f4.x; b = f4.y; c = f4.z; d = f4.w;
        } else { a = 1.f; b = 0.f; c = 0.f; d = 1.f; }

        // ---------------- invariants + polar (fp32, verified) ----------------
        const float x1 = a + d, y1 = c - b, x2 = a - d, y2 = c + b;
        const float h1v = sqrtf(x1 * x1 + y1 * y1);
        const float h2v = sqrtf(x2 * x2 + y2 * y2);
        const float s1 = 0.5f * (h1v + h2v), s2 = 0.5f * (h1v - h2v);
        const float ir = 1.0f / h1v;
        const float Rc = x1 * ir, Rs = y1 * ir;
        f16x8 iv;
        iv[0] = (_Float16)(s1 - 1.f);
        iv[1] = (_Float16)(s2 - 1.f);
        iv[2] = (_Float16)(a * a + c * c - 1.f);
        const float i3 = a * b + c * d;
        iv[3] = (_Float16)i3;
        iv[4] = (_Float16)i3;
        iv[5] = (_Float16)(b * b + d * d - 1.f);
        iv[6] = (_Float16)(a * d - b * c - 1.f);
        iv[7] = (_Float16)1.0f;
        *(f16x8*)(&invL[w][lane][0]) = iv;

        // ---------------- four 16-point quarter-passes (minimal live state) --------
        // Loop shape mirrors R13's PASSING serialized pass-loop: no MFMA register
        // state is live across the loop boundary (only invL, via LDS).
#pragma unroll 1
        for (int q4 = 0; q4 < 4; ++q4) {
            // B1 frag: B[k=8q+j][n=l15] = inv_k(point q4*16+l15); quad0 only
            const f16x8 B1 = (quad == 0)
                ? *(const f16x8*)(&invL[w][q4 * 16 + l15][0]) : zero8();

            // ---- layer 1 (transposed): this quarter's B2 in registers ----
            f16x8 B2[4];   // [s], 16 VGPRs
#pragma unroll
            for (int s = 0; s < 4; ++s) {
                const f16x8 aLo = (quad == 0) ? *(const f16x8*)(&W1A[2 * s][l15][0])     : zero8();
                const f16x8 aHi = (quad == 0) ? *(const f16x8*)(&W1A[2 * s + 1][l15][0]) : zero8();
                const f32x4 cz  = {0.f, 0.f, 0.f, 0.f};
                const f32x4 dLo = MFMA(aLo, B1, cz);   // ch = 32s    + 4q + r
                const f32x4 dHi = MFMA(aHi, B1, cz);   // ch = 32s+16 + 4q + r
                B2[s] = relu_pack8_rtn(dLo, dHi);
            }

            // ---- layers 2+3 fused, register-chained (fully unrolled) ----
            f32x4 acc3 = {0.f, 0.f, 0.f, 0.f};
#pragma unroll
            for (int s3 = 0; s3 < 4; ++s3) {           // mt2 pair (2*s3, 2*s3+1)
                f32x4 accE = *(const f32x4*)(&b2L[(2 * s3) * 16 + quad * 4]);
                f32x4 accO = *(const f32x4*)(&b2L[(2 * s3 + 1) * 16 + quad * 4]);
#pragma unroll
                for (int s = 0; s < 4; ++s) {
                    const f16x8 aE = *(const f16x8*)(&W2A[2 * s3][s][lane][0]);
                    const f16x8 aO = *(const f16x8*)(&W2A[2 * s3 + 1][s][lane][0]);
                    accE = MFMA(aE, B2[s], accE);
                    accO = MFMA(aO, B2[s], accO);
                }
                const f16x8 a3 = (l15 < 4) ? *(const f16x8*)(&W3A[s3][quad * 4 + l15][0]) : zero8();
                const f16x8 b3f = relu_pack8_rtz(accE, accO);
                acc3 = MFMA(a3, b3f, acc3);
            }

            // stage this quarter's x (+b3, pre-symmetrize, R10-verified ordering)
            // into invL rows [16*q4, 16*q4+16). Wave-private; quarter q4+1 reads
            // rows 16*(q4+1).. (untouched iv), program order within wave -> no race.
            if (quad == 0) {
                const f32x4 b3v4 = *(const f32x4*)(&b3L[0]);
                *(f16x8*)(&invL[w][q4 * 16 + l15][0]) =
                    __builtin_bit_cast(f16x8, acc3 + b3v4);
            }
        }

        // ---------------- epilogue: x via invL alias -> R@x + F ----------------
        const f32x4 xv = __builtin_bit_cast(f32x4, *(const f16x8*)(&invL[w][lane][0]));
        const float xm  = 0.5f * (xv[1] + xv[2]);
        const float d00 = Rc * xv[0] - Rs * xm;
        const float d01 = Rc * xm    - Rs * xv[3];
        const float d10 = Rs * xv[0] + Rc * xm;
        const float d11 = Rs * xm    + Rc * xv[3];
        if (p < N) {
            float4 o;
            o.x = a + d00; o.y = b + d01; o.z = c + d10; o.w = d + d11;
            *(float4*)(out + 4ll * p) = o;
        }
    }
}

extern "C" void kernel_launch(void* const* d_in, const int* in_sizes, int n_in,
                              void* d_out, int out_size, void* d_ws, size_t ws_size,
                              hipStream_t stream) {
    const float* F  = (const float*)d_in[0];
    const float* W1 = (const float*)d_in[1];
    const float* b1 = (const float*)d_in[2];
    const float* W2 = (const float*)d_in[3];
    const float* b2 = (const float*)d_in[4];
    const float* W3 = (const float*)d_in[5];
    const float* b3 = (const float*)d_in[6];
    float* out = (float*)d_out;
    const int N = in_sizes[0] / 4;
    const int ntiles = (N + 255) / 256;
    // grid 512 (R16 proved larger grids only add prepack overhead):
    // 2 blocks/CU x 256 CU; grid-stride keeps correctness at any residency.
    const int grid = ntiles < 512 ? ntiles : 512;
    DeformationCorrector_78967268704761_kernel<<<grid, 256, 0, stream>>>(
        F, W1, b1, W2, b2, W3, b3, out, N);
}